// Round 6
// baseline (778.791 us; speedup 1.0000x reference)
//
#include <hip/hip_runtime.h>
#include <stdint.h>

#define V_ITEMS 100000
#define EDIM    128
#define BATCH   4096
#define HLEN    50
#define TOPK    21

#define MT      64                      // batches per block in K2
#define MS      4                       // 16-row MFMA sub-blocks (MT/16)
#define VSPLIT  8                       // item-range splits: 3.2MB/range < 4MB XCD-L2
#define NWAVE   16                      // waves per block (1024 threads)
#define NCHUNK_TOT (V_ITEMS / 16)       // 6250 16-item chunks total
#define NITER   50                      // ceil(782/16)=49 -> 50 (even, double-buffer)
#define CAP2    256                     // per-batch candidate capacity (R4-proven)
#define NKEEP   32                      // superset kept per (batch, range)
#define NCAND   (NKEEP * VSPLIT)        // 256 candidates per batch into K3

typedef __attribute__((ext_vector_type(8))) short          bf16x8;
typedef __attribute__((ext_vector_type(4))) float          f32x4;
typedef __attribute__((ext_vector_type(8))) unsigned short u16x8;

__device__ inline unsigned short f2bf(float x) {           // RNE fp32->bf16
    unsigned u = __float_as_uint(x);
    return (unsigned short)((u + 0x7FFFu + ((u >> 16) & 1u)) >> 16);
}

// ---------------- K0: emb fp32 -> bf16 table in ws --------------------------
__global__ __launch_bounds__(256) void conv_bf16(
        const float* __restrict__ s, unsigned short* __restrict__ d) {
    size_t i = (size_t)blockIdx.x * 256 + threadIdx.x;     // 8 floats/thread
    const float4* sp = (const float4*)s + i * 2;
    float4 a = sp[0], b = sp[1];
    u16x8 o;
    o[0] = f2bf(a.x); o[1] = f2bf(a.y); o[2] = f2bf(a.z); o[3] = f2bf(a.w);
    o[4] = f2bf(b.x); o[5] = f2bf(b.y); o[6] = f2bf(b.z); o[7] = f2bf(b.w);
    *((u16x8*)d + i) = o;
}

// ---------------- K1: masked mean-pool queries -> bf16 + fp32 ---------------
__global__ __launch_bounds__(EDIM) void query_bf16(
        const int* __restrict__ seq, const int* __restrict__ len,
        const float* __restrict__ emb, unsigned short* __restrict__ qbf,
        float* __restrict__ qf) {
    int b = blockIdx.x, d = threadIdx.x;
    int n = len[b];
    float s = 0.f;
    for (int l = 0; l < n; l++)
        s += emb[(size_t)seq[b * HLEN + l] * EDIM + d];
    float q = s / (float)(n > 0 ? n : 1);
    qbf[b * EDIM + d] = f2bf(q);
    qf [b * EDIM + d] = q;
}

// ---- exact top-32 of a batch's candidate buffer: ballot-bisection on keys --
// CAP2 = 256 -> 4 elements per lane (verbatim from the R4-passing kernel).
__device__ inline void compact_batch(float* cv, int* ci, int* cnt, float* thr,
                                     int b, int lane) {
    int n = min(cnt[b], CAP2);
    float val[4]; int idx[4]; unsigned key[4];
    #pragma unroll
    for (int e = 0; e < 4; e++) {
        int i = lane + e * 64;
        if (i < n) {
            float v = cv[b * CAP2 + i];
            unsigned u = __float_as_uint(v);
            key[e] = (u & 0x80000000u) ? ~u : (u | 0x80000000u);
            val[e] = v; idx[e] = ci[b * CAP2 + i];
        } else { key[e] = 0u; val[e] = 0.f; idx[e] = 0; }
    }
    unsigned cur = 0u;                 // max T with count(key >= T) >= 32
    #pragma unroll 1
    for (int bit = 31; bit >= 0; bit--) {
        unsigned mid = cur | (1u << bit);
        int c = 0;
        #pragma unroll
        for (int e = 0; e < 4; e++)
            c += __popcll(__ballot(key[e] >= mid));
        if (c >= NKEEP) cur = mid;
    }
    int base = 0;                      // ballot prefix-sum compaction, no atomics
    #pragma unroll
    for (int e = 0; e < 4; e++) {
        bool keep = key[e] >= cur;
        unsigned long long m = __ballot(keep);
        int p = base + (int)__popcll(m & ((1ull << lane) - 1ull));
        if (keep && p < NKEEP) { cv[b * CAP2 + p] = val[e]; ci[b * CAP2 + p] = idx[e]; }
        base += (int)__popcll(m);
    }
    if (lane == 0) {
        cnt[b] = NKEEP;
        thr[b] = (cur & 0x80000000u) ? __uint_as_float(cur ^ 0x80000000u)
                                     : __uint_as_float(~cur);
    }
}

// ---------------- K2: bf16-MFMA scoring + fused per-range top-32 ------------
// grid = 64 batch-groups x 8 V-ranges = 512 blocks, 1024 threads (16 waves),
// 1 block/CU (LDS 128.5KB) -> 4 waves/SIMD.
//
// R5 post-mortem: branchless ballot-insert REGRESSED (355->477us, VALUBusy
// 19->44%) -- unconditional per-k VALU+ds_write costs more than the branchy
// path's cbranch_execz skips. Reverted to R4's atomic insert verbatim.
// R4 analysis: 69% idle issue at 2 waves/SIMD (mixed LLC-load latency +
// LDS-atomic chains). Levers here: (1) NWAVE=16 -> 4 waves/SIMD to fill
// idle slots; (2) VSPLIT=8 -> 3.2MB range fits the 4MB per-XCD L2, and
// r=blockIdx&7 aligns ranges to the XCD round-robin -> B-loads become L2
// hits after warm-up. Overflow math at 256 items/row/iter: iter0 fills
// exactly CAP2=256 (compacted at first event); thereafter E[cnt] <= 204
// even if the >96 trigger never fired (4-sigma incl.) < 256.
__global__ __launch_bounds__(1024, 4) void score_topk(
        const unsigned short* __restrict__ qbf,
        const unsigned short* __restrict__ ebf,
        int* __restrict__ candOut) {
    __shared__ float cv[MT * CAP2];    // 64 KB
    __shared__ int   ci[MT * CAP2];    // 64 KB
    __shared__ int   cnt[MT];
    __shared__ float thr[MT];

    const int tid  = threadIdx.x;
    const int lane = tid & 63;
    const int w    = tid >> 6;                       // wave 0..15
    const int r    = blockIdx.x & (VSPLIT - 1);      // V-range (== XCD id)
    const int mg   = blockIdx.x / VSPLIT;            // batch group
    const int b0   = mg * MT;
    const int n15  = lane & 15, quad = lane >> 4;

    const int cstart = (r * NCHUNK_TOT) / VSPLIT;
    const int nch    = ((r + 1) * NCHUNK_TOT) / VSPLIT - cstart;  // 781/782

    if (tid < MT) { cnt[tid] = 0; thr[tid] = -INFINITY; }
    __syncthreads();

    // resident A-fragments: 4 msubs x 4 K-steps (64 VGPRs)
    bf16x8 afr[MS][4];
    #pragma unroll
    for (int ms = 0; ms < MS; ms++)
        #pragma unroll
        for (int t = 0; t < 4; t++)
            afr[ms][t] = *(const bf16x8*)(qbf + (b0 + ms * 16 + n15) * EDIM
                                          + t * 32 + quad * 8);
    float thrR[MS * 4];
    #pragma unroll
    for (int i = 0; i < MS * 4; i++) thrR[i] = -INFINITY;

    const unsigned short* bbase = ebf + ((size_t)cstart * 16 + n15) * EDIM + quad * 8;

    int nextEvt = 1;

    // one iteration: MFMA+insert on `cur`, prefetch chunk(iter+1) into `nxt`
    auto body = [&](int iter, bf16x8 (&cur)[4], bf16x8 (&nxt)[4]) {
        {   // prefetch next iteration's B fragments
            int nit   = (iter + 1 < NITER) ? (iter + 1) : iter;
            int pch   = nit * NWAVE + w;
            int pcc   = (pch < nch) ? pch : (nch - 1);
            const unsigned short* bp = bbase + (size_t)pcc * (16 * EDIM);
            #pragma unroll
            for (int t = 0; t < 4; t++) nxt[t] = *(const bf16x8*)(bp + t * 32);
        }
        f32x4 acc[MS];
        #pragma unroll
        for (int ms = 0; ms < MS; ms++) acc[ms] = (f32x4){0.f, 0.f, 0.f, 0.f};
        #pragma unroll
        for (int t = 0; t < 4; t++)
            #pragma unroll
            for (int ms = 0; ms < MS; ms++)
                acc[ms] = __builtin_amdgcn_mfma_f32_16x16x32_bf16(afr[ms][t], cur[t], acc[ms], 0, 0, 0);

        int chunk = iter * NWAVE + w;
        bool act  = chunk < nch;                     // wave-uniform
        // C/D: item n = lane&15 (col), batch row = quad*4 + reg  [m89/m91]
        if (act) {
            int item = (cstart + chunk) * 16 + n15;
            float s[MS * 4]; bool hit = false;
            #pragma unroll
            for (int k = 0; k < MS * 4; k++) {
                float v = acc[k >> 2][k & 3];
                s[k] = v;
                hit |= (v > thrR[k]);
            }
            if (__any(hit)) {                        // wave-uniform slow path
                #pragma unroll
                for (int k = 0; k < MS * 4; k++) {
                    if (s[k] > thrR[k]) {
                        int row = (k >> 2) * 16 + (quad << 2) + (k & 3);
                        int pz = atomicAdd(&cnt[row], 1);
                        if (pz < CAP2) { cv[row * CAP2 + pz] = s[k]; ci[row * CAP2 + pz] = item; }
                    }
                }
            }
        }
        // static compaction schedule: iters 1,2,4,...,32, and the final iter.
        // Uniform across waves -> barrier counts always match. Trigger cnt>96
        // with CAP2=256: R4-proven headroom.
        if (iter + 1 == nextEvt || iter + 1 == NITER) {
            if (iter + 1 == nextEvt) nextEvt <<= 1;
            bool fin = (iter + 1 == NITER);
            __syncthreads();
            #pragma unroll 1
            for (int j = 0; j < MT / NWAVE; j++) {   // 4 rows per wave
                int b = w * (MT / NWAVE) + j;
                if (fin || cnt[b] > 96) compact_batch(cv, ci, cnt, thr, b, lane);
            }
            __syncthreads();
            #pragma unroll
            for (int ms = 0; ms < MS; ms++)
                #pragma unroll
                for (int rr = 0; rr < 4; rr++)
                    thrR[ms * 4 + rr] = thr[ms * 16 + (quad << 2) + rr];
        }
    };

    bf16x8 bA[4], bB[4];
    {   // preload iter 0
        int cc0 = (w < nch) ? w : (nch - 1);
        const unsigned short* bp = bbase + (size_t)cc0 * (16 * EDIM);
        #pragma unroll
        for (int t = 0; t < 4; t++) bA[t] = *(const bf16x8*)(bp + t * 32);
    }
    for (int iter = 0; iter < NITER; iter += 2) {    // NITER even: no tail
        body(iter,     bA, bB);
        body(iter + 1, bB, bA);
    }

    // final compact guaranteed cnt==32 per batch; emit candidate indices
    for (int j = 0; j < MT / NWAVE; j++) {
        int b = w * (MT / NWAVE) + j;
        if (lane < NKEEP)
            candOut[(b0 + b) * NCAND + r * NKEEP + lane] = ci[b * CAP2 + lane];
    }
}

// ---------------- K3: fp64 rescore of 256 candidates, exact top-21 ----------
__global__ __launch_bounds__(512) void rescore(
        const float* __restrict__ qf, const float* __restrict__ emb,
        const int* __restrict__ cand, float* __restrict__ out) {
    __shared__ double qd[EDIM];
    __shared__ double sv[NCAND];
    __shared__ int    si[NCAND];
    int b = blockIdx.x, t = threadIdx.x;
    if (t < EDIM) qd[t] = (double)qf[b * EDIM + t];  // precomputed in K1
    __syncthreads();

    int c = t >> 1, h = t & 1;                       // 2 threads per candidate
    int idx = cand[b * NCAND + c];
    const float4* ev = (const float4*)(emb + (size_t)idx * EDIM + h * 64);
    double part = 0.0;
    #pragma unroll 4
    for (int j = 0; j < 16; j++) {
        float4 e = ev[j];
        int d = h * 64 + j * 4;
        part += qd[d] * (double)e.x + qd[d + 1] * (double)e.y
              + qd[d + 2] * (double)e.z + qd[d + 3] * (double)e.w;
    }
    part += __shfl_xor(part, 1);                     // combine halves
    if (h == 0) { sv[c] = part; si[c] = idx; }
    __syncthreads();

    if (t < NCAND) {                                 // rank among 256 (ties: low idx)
        double v = sv[t]; int id = si[t];
        int rank = 0;
        for (int j = 0; j < NCAND; j++) {
            double vj = sv[j]; int ij = si[j];
            rank += (vj > v || (vj == v && ij < id)) ? 1 : 0;
        }
        if (rank < TOPK) {
            out[(size_t)b * TOPK + rank] = (float)v;
            out[(size_t)BATCH * TOPK + (size_t)b * TOPK + rank] = (float)id;
        }
    }
}

extern "C" void kernel_launch(void* const* d_in, const int* in_sizes, int n_in,
                              void* d_out, int out_size, void* d_ws, size_t ws_size,
                              hipStream_t stream) {
    const int*   seq = (const int*)d_in[0];
    const int*   len = (const int*)d_in[1];
    const float* emb = (const float*)d_in[2];
    float* out = (float*)d_out;

    // ws: q_bf [4096*128 u16] | emb_bf [100000*128 u16] | cand [4096*256 i32]
    //     | q_f32 [4096*128 f32]   (~32.6 MB total)
    unsigned short* qbf  = (unsigned short*)d_ws;
    unsigned short* ebf  = qbf + (size_t)BATCH * EDIM;
    int*            cand = (int*)(ebf + (size_t)V_ITEMS * EDIM);
    float*          qf   = (float*)(cand + (size_t)BATCH * NCAND);

    conv_bf16 <<<(V_ITEMS * EDIM) / (256 * 8), 256, 0, stream>>>(emb, ebf);
    query_bf16<<<BATCH, EDIM, 0, stream>>>(seq, len, emb, qbf, qf);
    score_topk<<<(BATCH / MT) * VSPLIT, 1024, 0, stream>>>(qbf, ebf, cand);
    rescore   <<<BATCH, 512, 0, stream>>>(qf, emb, cand, out);
}

// Round 7
// 630.524 us; speedup vs baseline: 1.2351x; 1.2351x over previous
//
#include <hip/hip_runtime.h>
#include <stdint.h>

#define V_ITEMS 100000
#define EDIM    128
#define BATCH   4096
#define HLEN    50
#define TOPK    21

#define MT      64                      // batches per block in K2
#define MS      4                       // 16-row MFMA sub-blocks (MT/16)
#define VSPLIT  8                       // item-range splits: 3.2MB/range < 4MB XCD-L2
#define NWAVE   12                      // waves per block (768 thr) -> 3 waves/SIMD
#define NCHUNK_TOT (V_ITEMS / 16)       // 6250 16-item chunks total
#define NITER   66                      // ceil(782/12)=66 (even, double-buffer)
#define CAP2    256                     // per-batch candidate capacity (R4-proven)
#define NKEEP   32                      // superset kept per (batch, range)
#define NCAND   (NKEEP * VSPLIT)        // 256 candidates per batch into K3

typedef __attribute__((ext_vector_type(8))) short          bf16x8;
typedef __attribute__((ext_vector_type(4))) float          f32x4;
typedef __attribute__((ext_vector_type(8))) unsigned short u16x8;

__device__ inline unsigned short f2bf(float x) {           // RNE fp32->bf16
    unsigned u = __float_as_uint(x);
    return (unsigned short)((u + 0x7FFFu + ((u >> 16) & 1u)) >> 16);
}

// ---------------- K0: emb fp32 -> bf16 table in ws --------------------------
__global__ __launch_bounds__(256) void conv_bf16(
        const float* __restrict__ s, unsigned short* __restrict__ d) {
    size_t i = (size_t)blockIdx.x * 256 + threadIdx.x;     // 8 floats/thread
    const float4* sp = (const float4*)s + i * 2;
    float4 a = sp[0], b = sp[1];
    u16x8 o;
    o[0] = f2bf(a.x); o[1] = f2bf(a.y); o[2] = f2bf(a.z); o[3] = f2bf(a.w);
    o[4] = f2bf(b.x); o[5] = f2bf(b.y); o[6] = f2bf(b.z); o[7] = f2bf(b.w);
    *((u16x8*)d + i) = o;
}

// ---------------- K1: masked mean-pool queries -> bf16 + fp32 ---------------
__global__ __launch_bounds__(EDIM) void query_bf16(
        const int* __restrict__ seq, const int* __restrict__ len,
        const float* __restrict__ emb, unsigned short* __restrict__ qbf,
        float* __restrict__ qf) {
    int b = blockIdx.x, d = threadIdx.x;
    int n = len[b];
    float s = 0.f;
    for (int l = 0; l < n; l++)
        s += emb[(size_t)seq[b * HLEN + l] * EDIM + d];
    float q = s / (float)(n > 0 ? n : 1);
    qbf[b * EDIM + d] = f2bf(q);
    qf [b * EDIM + d] = q;
}

// ---- exact top-32 of a batch's candidate buffer: ballot-bisection on keys --
// CAP2 = 256 -> 4 elements per lane (verbatim from the R4-passing kernel).
__device__ inline void compact_batch(float* cv, int* ci, int* cnt, float* thr,
                                     int b, int lane) {
    int n = min(cnt[b], CAP2);
    float val[4]; int idx[4]; unsigned key[4];
    #pragma unroll
    for (int e = 0; e < 4; e++) {
        int i = lane + e * 64;
        if (i < n) {
            float v = cv[b * CAP2 + i];
            unsigned u = __float_as_uint(v);
            key[e] = (u & 0x80000000u) ? ~u : (u | 0x80000000u);
            val[e] = v; idx[e] = ci[b * CAP2 + i];
        } else { key[e] = 0u; val[e] = 0.f; idx[e] = 0; }
    }
    unsigned cur = 0u;                 // max T with count(key >= T) >= 32
    #pragma unroll 1
    for (int bit = 31; bit >= 0; bit--) {
        unsigned mid = cur | (1u << bit);
        int c = 0;
        #pragma unroll
        for (int e = 0; e < 4; e++)
            c += __popcll(__ballot(key[e] >= mid));
        if (c >= NKEEP) cur = mid;
    }
    int base = 0;                      // ballot prefix-sum compaction, no atomics
    #pragma unroll
    for (int e = 0; e < 4; e++) {
        bool keep = key[e] >= cur;
        unsigned long long m = __ballot(keep);
        int p = base + (int)__popcll(m & ((1ull << lane) - 1ull));
        if (keep && p < NKEEP) { cv[b * CAP2 + p] = val[e]; ci[b * CAP2 + p] = idx[e]; }
        base += (int)__popcll(m);
    }
    if (lane == 0) {
        cnt[b] = NKEEP;
        thr[b] = (cur & 0x80000000u) ? __uint_as_float(cur ^ 0x80000000u)
                                     : __uint_as_float(~cur);
    }
}

// ---------------- K2: bf16-MFMA scoring + fused per-range top-32 ------------
// grid = 64 batch-groups x 8 V-ranges = 512 blocks, 768 threads (12 waves),
// 1 block/CU (LDS 131.6KB) -> 3 waves/SIMD, 2 dispatch tranches.
//
// R6 post-mortem: 1024-thread blocks force >=4 waves/SIMD -> VGPR cap 128 <
// ~150 needed -> scratch spills (VGPR_Count 64, WRITE_SIZE 35MB) -> 577us.
// 768 threads = 3 waves/SIMD: launch_bounds(768,3) gives a 170-VGPR budget,
// no spill, while restoring +50% latency-hiding waves over R4's 2/SIMD
// (R4 was 69% issue-idle; B-loads already ~98% L2-hit per FETCH_SIZE, so
// the exposed cost is L2-hit latency + insert chains -> TLP covers it).
// Candidate dynamics identical class to R4-proven: iter0 floods 192<=256,
// windows E~+22 (trigger>96), worst stale-thr peak ~120 << CAP2=256.
__global__ __launch_bounds__(768, 3) void score_topk(
        const unsigned short* __restrict__ qbf,
        const unsigned short* __restrict__ ebf,
        int* __restrict__ candOut) {
    __shared__ float cv[MT * CAP2];    // 64 KB
    __shared__ int   ci[MT * CAP2];    // 64 KB
    __shared__ int   cnt[MT];
    __shared__ float thr[MT];

    const int tid  = threadIdx.x;
    const int lane = tid & 63;
    const int w    = tid >> 6;                       // wave 0..11
    const int r    = blockIdx.x & (VSPLIT - 1);      // V-range (== XCD id)
    const int mg   = blockIdx.x / VSPLIT;            // batch group
    const int b0   = mg * MT;
    const int n15  = lane & 15, quad = lane >> 4;

    const int cstart = (r * NCHUNK_TOT) / VSPLIT;
    const int nch    = ((r + 1) * NCHUNK_TOT) / VSPLIT - cstart;  // 781/782

    if (tid < MT) { cnt[tid] = 0; thr[tid] = -INFINITY; }
    __syncthreads();

    // resident A-fragments: 4 msubs x 4 K-steps (64 VGPRs)
    bf16x8 afr[MS][4];
    #pragma unroll
    for (int ms = 0; ms < MS; ms++)
        #pragma unroll
        for (int t = 0; t < 4; t++)
            afr[ms][t] = *(const bf16x8*)(qbf + (b0 + ms * 16 + n15) * EDIM
                                          + t * 32 + quad * 8);
    float thrR[MS * 4];
    #pragma unroll
    for (int i = 0; i < MS * 4; i++) thrR[i] = -INFINITY;

    const unsigned short* bbase = ebf + ((size_t)cstart * 16 + n15) * EDIM + quad * 8;

    int nextEvt = 1;

    // one iteration: MFMA+insert on `cur`, prefetch chunk(iter+1) into `nxt`
    auto body = [&](int iter, bf16x8 (&cur)[4], bf16x8 (&nxt)[4]) {
        {   // prefetch next iteration's B fragments
            int nit   = (iter + 1 < NITER) ? (iter + 1) : iter;
            int pch   = nit * NWAVE + w;
            int pcc   = (pch < nch) ? pch : (nch - 1);
            const unsigned short* bp = bbase + (size_t)pcc * (16 * EDIM);
            #pragma unroll
            for (int t = 0; t < 4; t++) nxt[t] = *(const bf16x8*)(bp + t * 32);
        }
        f32x4 acc[MS];
        #pragma unroll
        for (int ms = 0; ms < MS; ms++) acc[ms] = (f32x4){0.f, 0.f, 0.f, 0.f};
        #pragma unroll
        for (int t = 0; t < 4; t++)
            #pragma unroll
            for (int ms = 0; ms < MS; ms++)
                acc[ms] = __builtin_amdgcn_mfma_f32_16x16x32_bf16(afr[ms][t], cur[t], acc[ms], 0, 0, 0);

        int chunk = iter * NWAVE + w;
        bool act  = chunk < nch;                     // wave-uniform
        // C/D: item n = lane&15 (col), batch row = quad*4 + reg  [m89/m91]
        if (act) {
            int item = (cstart + chunk) * 16 + n15;
            float s[MS * 4]; bool hit = false;
            #pragma unroll
            for (int k = 0; k < MS * 4; k++) {
                float v = acc[k >> 2][k & 3];
                s[k] = v;
                hit |= (v > thrR[k]);
            }
            if (__any(hit)) {                        // wave-uniform slow path
                #pragma unroll
                for (int k = 0; k < MS * 4; k++) {
                    if (s[k] > thrR[k]) {
                        int row = (k >> 2) * 16 + (quad << 2) + (k & 3);
                        int pz = atomicAdd(&cnt[row], 1);
                        if (pz < CAP2) { cv[row * CAP2 + pz] = s[k]; ci[row * CAP2 + pz] = item; }
                    }
                }
            }
        }
        // static compaction schedule: iters 1,2,4,...,64, and the final iter.
        // Uniform across waves -> barrier counts always match. Trigger cnt>96
        // with CAP2=256: R4-proven headroom.
        if (iter + 1 == nextEvt || iter + 1 == NITER) {
            if (iter + 1 == nextEvt) nextEvt <<= 1;
            bool fin = (iter + 1 == NITER);
            __syncthreads();
            #pragma unroll 1
            for (int b = w; b < MT; b += NWAVE) {    // rows striped over 12 waves
                if (fin || cnt[b] > 96) compact_batch(cv, ci, cnt, thr, b, lane);
            }
            __syncthreads();
            #pragma unroll
            for (int ms = 0; ms < MS; ms++)
                #pragma unroll
                for (int rr = 0; rr < 4; rr++)
                    thrR[ms * 4 + rr] = thr[ms * 16 + (quad << 2) + rr];
        }
    };

    bf16x8 bA[4], bB[4];
    {   // preload iter 0
        int cc0 = (w < nch) ? w : (nch - 1);
        const unsigned short* bp = bbase + (size_t)cc0 * (16 * EDIM);
        #pragma unroll
        for (int t = 0; t < 4; t++) bA[t] = *(const bf16x8*)(bp + t * 32);
    }
    for (int iter = 0; iter < NITER; iter += 2) {    // NITER even: no tail
        body(iter,     bA, bB);
        body(iter + 1, bB, bA);
    }

    // final compact guaranteed cnt==32 per batch; emit candidate indices
    for (int b = w; b < MT; b += NWAVE) {
        if (lane < NKEEP)
            candOut[(b0 + b) * NCAND + r * NKEEP + lane] = ci[b * CAP2 + lane];
    }
}

// ---------------- K3: fp64 rescore of 256 candidates, exact top-21 ----------
__global__ __launch_bounds__(512) void rescore(
        const float* __restrict__ qf, const float* __restrict__ emb,
        const int* __restrict__ cand, float* __restrict__ out) {
    __shared__ double qd[EDIM];
    __shared__ double sv[NCAND];
    __shared__ int    si[NCAND];
    int b = blockIdx.x, t = threadIdx.x;
    if (t < EDIM) qd[t] = (double)qf[b * EDIM + t];  // precomputed in K1
    __syncthreads();

    int c = t >> 1, h = t & 1;                       // 2 threads per candidate
    int idx = cand[b * NCAND + c];
    const float4* ev = (const float4*)(emb + (size_t)idx * EDIM + h * 64);
    double part = 0.0;
    #pragma unroll 4
    for (int j = 0; j < 16; j++) {
        float4 e = ev[j];
        int d = h * 64 + j * 4;
        part += qd[d] * (double)e.x + qd[d + 1] * (double)e.y
              + qd[d + 2] * (double)e.z + qd[d + 3] * (double)e.w;
    }
    part += __shfl_xor(part, 1);                     // combine halves
    if (h == 0) { sv[c] = part; si[c] = idx; }
    __syncthreads();

    if (t < NCAND) {                                 // rank among 256 (ties: low idx)
        double v = sv[t]; int id = si[t];
        int rank = 0;
        for (int j = 0; j < NCAND; j++) {
            double vj = sv[j]; int ij = si[j];
            rank += (vj > v || (vj == v && ij < id)) ? 1 : 0;
        }
        if (rank < TOPK) {
            out[(size_t)b * TOPK + rank] = (float)v;
            out[(size_t)BATCH * TOPK + (size_t)b * TOPK + rank] = (float)id;
        }
    }
}

extern "C" void kernel_launch(void* const* d_in, const int* in_sizes, int n_in,
                              void* d_out, int out_size, void* d_ws, size_t ws_size,
                              hipStream_t stream) {
    const int*   seq = (const int*)d_in[0];
    const int*   len = (const int*)d_in[1];
    const float* emb = (const float*)d_in[2];
    float* out = (float*)d_out;

    // ws: q_bf [4096*128 u16] | emb_bf [100000*128 u16] | cand [4096*256 i32]
    //     | q_f32 [4096*128 f32]   (~32.6 MB total)
    unsigned short* qbf  = (unsigned short*)d_ws;
    unsigned short* ebf  = qbf + (size_t)BATCH * EDIM;
    int*            cand = (int*)(ebf + (size_t)V_ITEMS * EDIM);
    float*          qf   = (float*)(cand + (size_t)BATCH * NCAND);

    conv_bf16 <<<(V_ITEMS * EDIM) / (256 * 8), 256, 0, stream>>>(emb, ebf);
    query_bf16<<<BATCH, EDIM, 0, stream>>>(seq, len, emb, qbf, qf);
    score_topk<<<(BATCH / MT) * VSPLIT, 768, 0, stream>>>(qbf, ebf, cand);
    rescore   <<<BATCH, 512, 0, stream>>>(qf, emb, cand, out);
}

// Round 8
// 456.896 us; speedup vs baseline: 1.7045x; 1.3800x over previous
//
#include <hip/hip_runtime.h>
#include <stdint.h>

#define V_ITEMS 100000
#define EDIM    128
#define BATCH   4096
#define HLEN    50
#define TOPK    21

#define MT      64                      // batches per block in K2
#define MS      4                       // 16-row MFMA sub-blocks (MT/16)
#define VSPLIT  4                       // item-range splits (R4-proven overhead level)
#define NWAVE   12                      // waves per block (768 thr) -> 3 waves/SIMD
#define NCHUNK_TOT (V_ITEMS / 16)       // 6250 16-item chunks total
#define NITER   132                     // ceil(1563/12)=131 -> 132 (even)
#define CAP2    256                     // per-batch candidate capacity (R4-proven)
#define NKEEP   32                      // superset kept per (batch, range)
#define NCAND   (NKEEP * VSPLIT)        // 128 candidates per batch into K3

typedef __attribute__((ext_vector_type(8))) short          bf16x8;
typedef __attribute__((ext_vector_type(4))) float          f32x4;
typedef __attribute__((ext_vector_type(8))) unsigned short u16x8;

__device__ inline unsigned short f2bf(float x) {           // RNE fp32->bf16
    unsigned u = __float_as_uint(x);
    return (unsigned short)((u + 0x7FFFu + ((u >> 16) & 1u)) >> 16);
}

// ---------------- K0: emb fp32 -> bf16 table in ws --------------------------
__global__ __launch_bounds__(256) void conv_bf16(
        const float* __restrict__ s, unsigned short* __restrict__ d) {
    size_t i = (size_t)blockIdx.x * 256 + threadIdx.x;     // 8 floats/thread
    const float4* sp = (const float4*)s + i * 2;
    float4 a = sp[0], b = sp[1];
    u16x8 o;
    o[0] = f2bf(a.x); o[1] = f2bf(a.y); o[2] = f2bf(a.z); o[3] = f2bf(a.w);
    o[4] = f2bf(b.x); o[5] = f2bf(b.y); o[6] = f2bf(b.z); o[7] = f2bf(b.w);
    *((u16x8*)d + i) = o;
}

// ---------------- K1: masked mean-pool queries -> bf16 + fp32 ---------------
__global__ __launch_bounds__(EDIM) void query_bf16(
        const int* __restrict__ seq, const int* __restrict__ len,
        const float* __restrict__ emb, unsigned short* __restrict__ qbf,
        float* __restrict__ qf) {
    int b = blockIdx.x, d = threadIdx.x;
    int n = len[b];
    float s = 0.f;
    for (int l = 0; l < n; l++)
        s += emb[(size_t)seq[b * HLEN + l] * EDIM + d];
    float q = s / (float)(n > 0 ? n : 1);
    qbf[b * EDIM + d] = f2bf(q);
    qf [b * EDIM + d] = q;
}

// ---- exact top-32 of a batch's candidate buffer: ballot-bisection on keys --
// CAP2 = 256 -> 4 elements per lane (verbatim from the R4-passing kernel).
__device__ inline void compact_batch(float* cv, int* ci, int* cnt, float* thr,
                                     int b, int lane) {
    int n = min(cnt[b], CAP2);
    float val[4]; int idx[4]; unsigned key[4];
    #pragma unroll
    for (int e = 0; e < 4; e++) {
        int i = lane + e * 64;
        if (i < n) {
            float v = cv[b * CAP2 + i];
            unsigned u = __float_as_uint(v);
            key[e] = (u & 0x80000000u) ? ~u : (u | 0x80000000u);
            val[e] = v; idx[e] = ci[b * CAP2 + i];
        } else { key[e] = 0u; val[e] = 0.f; idx[e] = 0; }
    }
    unsigned cur = 0u;                 // max T with count(key >= T) >= 32
    #pragma unroll 1
    for (int bit = 31; bit >= 0; bit--) {
        unsigned mid = cur | (1u << bit);
        int c = 0;
        #pragma unroll
        for (int e = 0; e < 4; e++)
            c += __popcll(__ballot(key[e] >= mid));
        if (c >= NKEEP) cur = mid;
    }
    int base = 0;                      // ballot prefix-sum compaction, no atomics
    #pragma unroll
    for (int e = 0; e < 4; e++) {
        bool keep = key[e] >= cur;
        unsigned long long m = __ballot(keep);
        int p = base + (int)__popcll(m & ((1ull << lane) - 1ull));
        if (keep && p < NKEEP) { cv[b * CAP2 + p] = val[e]; ci[b * CAP2 + p] = idx[e]; }
        base += (int)__popcll(m);
    }
    if (lane == 0) {
        cnt[b] = NKEEP;
        thr[b] = (cur & 0x80000000u) ? __uint_as_float(cur ^ 0x80000000u)
                                     : __uint_as_float(~cur);
    }
}

// ---------------- K2: bf16-MFMA scoring + fused per-range top-32 ------------
// grid = 64 batch-groups x 4 V-ranges = 256 blocks (1/CU, SINGLE tranche),
// 768 threads = 12 waves = 3 waves/SIMD (LDS 131.6KB caps at 1 block/CU).
//
// R7 post-mortem: NWAVE=12 worked (VGPR 80, no spill, VALUBusy 19->24%) but
// VSPLIT=8 doubled insert+compact overhead (bank-conflicts 2.9M->6.2M,
// inserts 3.5M->6.3M) and the 2-tranche grid paid the iter-0 flood twice ->
// net 427us vs R4's 355us. This round: the untested cell -- R4's exact
// algorithm (VSPLIT=4, CAP2=256, trigger>96, branchy atomic insert) with
// NWAVE=12 only. Single hypothesis: R4 idles 69% of issue slots at 2
// waves/SIMD (exposed L2-hit latency, allocator coalesces bA/bB); +50%
// waves covers it. NWAVE=12 dynamics (192-item/row flood <= 256) are
// R7-field-proven; VSPLIT=4 windows are R4-field-proven.
__global__ __launch_bounds__(768, 3) void score_topk(
        const unsigned short* __restrict__ qbf,
        const unsigned short* __restrict__ ebf,
        int* __restrict__ candOut) {
    __shared__ float cv[MT * CAP2];    // 64 KB
    __shared__ int   ci[MT * CAP2];    // 64 KB
    __shared__ int   cnt[MT];
    __shared__ float thr[MT];

    const int tid  = threadIdx.x;
    const int lane = tid & 63;
    const int w    = tid >> 6;                       // wave 0..11
    const int r    = blockIdx.x & (VSPLIT - 1);      // V-range
    const int mg   = blockIdx.x / VSPLIT;            // batch group
    const int b0   = mg * MT;
    const int n15  = lane & 15, quad = lane >> 4;

    const int cstart = (r * NCHUNK_TOT) / VSPLIT;
    const int nch    = ((r + 1) * NCHUNK_TOT) / VSPLIT - cstart;  // 1562/1563

    if (tid < MT) { cnt[tid] = 0; thr[tid] = -INFINITY; }
    __syncthreads();

    // resident A-fragments: 4 msubs x 4 K-steps (64 VGPRs)
    bf16x8 afr[MS][4];
    #pragma unroll
    for (int ms = 0; ms < MS; ms++)
        #pragma unroll
        for (int t = 0; t < 4; t++)
            afr[ms][t] = *(const bf16x8*)(qbf + (b0 + ms * 16 + n15) * EDIM
                                          + t * 32 + quad * 8);
    float thrR[MS * 4];
    #pragma unroll
    for (int i = 0; i < MS * 4; i++) thrR[i] = -INFINITY;

    const unsigned short* bbase = ebf + ((size_t)cstart * 16 + n15) * EDIM + quad * 8;

    int nextEvt = 1;

    // one iteration: MFMA+insert on `cur`, prefetch chunk(iter+1) into `nxt`
    auto body = [&](int iter, bf16x8 (&cur)[4], bf16x8 (&nxt)[4]) {
        {   // prefetch next iteration's B fragments
            int nit   = (iter + 1 < NITER) ? (iter + 1) : iter;
            int pch   = nit * NWAVE + w;
            int pcc   = (pch < nch) ? pch : (nch - 1);
            const unsigned short* bp = bbase + (size_t)pcc * (16 * EDIM);
            #pragma unroll
            for (int t = 0; t < 4; t++) nxt[t] = *(const bf16x8*)(bp + t * 32);
        }
        f32x4 acc[MS];
        #pragma unroll
        for (int ms = 0; ms < MS; ms++) acc[ms] = (f32x4){0.f, 0.f, 0.f, 0.f};
        #pragma unroll
        for (int t = 0; t < 4; t++)
            #pragma unroll
            for (int ms = 0; ms < MS; ms++)
                acc[ms] = __builtin_amdgcn_mfma_f32_16x16x32_bf16(afr[ms][t], cur[t], acc[ms], 0, 0, 0);

        int chunk = iter * NWAVE + w;
        bool act  = chunk < nch;                     // wave-uniform
        // C/D: item n = lane&15 (col), batch row = quad*4 + reg  [m89/m91]
        if (act) {
            int item = (cstart + chunk) * 16 + n15;
            float s[MS * 4]; bool hit = false;
            #pragma unroll
            for (int k = 0; k < MS * 4; k++) {
                float v = acc[k >> 2][k & 3];
                s[k] = v;
                hit |= (v > thrR[k]);
            }
            if (__any(hit)) {                        // wave-uniform slow path
                #pragma unroll
                for (int k = 0; k < MS * 4; k++) {
                    if (s[k] > thrR[k]) {
                        int row = (k >> 2) * 16 + (quad << 2) + (k & 3);
                        int pz = atomicAdd(&cnt[row], 1);
                        if (pz < CAP2) { cv[row * CAP2 + pz] = s[k]; ci[row * CAP2 + pz] = item; }
                    }
                }
            }
        }
        // static compaction schedule: iters 1,2,4,...,128, and the final iter.
        // Uniform across waves -> barrier counts always match. Trigger cnt>96
        // with CAP2=256: R4-proven headroom.
        if (iter + 1 == nextEvt || iter + 1 == NITER) {
            if (iter + 1 == nextEvt) nextEvt <<= 1;
            bool fin = (iter + 1 == NITER);
            __syncthreads();
            #pragma unroll 1
            for (int b = w; b < MT; b += NWAVE) {    // rows striped over 12 waves
                if (fin || cnt[b] > 96) compact_batch(cv, ci, cnt, thr, b, lane);
            }
            __syncthreads();
            #pragma unroll
            for (int ms = 0; ms < MS; ms++)
                #pragma unroll
                for (int rr = 0; rr < 4; rr++)
                    thrR[ms * 4 + rr] = thr[ms * 16 + (quad << 2) + rr];
        }
    };

    bf16x8 bA[4], bB[4];
    {   // preload iter 0
        int cc0 = (w < nch) ? w : (nch - 1);
        const unsigned short* bp = bbase + (size_t)cc0 * (16 * EDIM);
        #pragma unroll
        for (int t = 0; t < 4; t++) bA[t] = *(const bf16x8*)(bp + t * 32);
    }
    for (int iter = 0; iter < NITER; iter += 2) {    // NITER even: no tail
        body(iter,     bA, bB);
        body(iter + 1, bB, bA);
    }

    // final compact guaranteed cnt==32 per batch; emit candidate indices
    for (int b = w; b < MT; b += NWAVE) {
        if (lane < NKEEP)
            candOut[(b0 + b) * NCAND + r * NKEEP + lane] = ci[b * CAP2 + lane];
    }
}

// ---------------- K3: fp64 rescore of 128 candidates, exact top-21 ----------
__global__ __launch_bounds__(256) void rescore(
        const float* __restrict__ qf, const float* __restrict__ emb,
        const int* __restrict__ cand, float* __restrict__ out) {
    __shared__ double qd[EDIM];
    __shared__ double sv[NCAND];
    __shared__ int    si[NCAND];
    int b = blockIdx.x, t = threadIdx.x;
    if (t < EDIM) qd[t] = (double)qf[b * EDIM + t];  // precomputed in K1
    __syncthreads();

    int c = t >> 1, h = t & 1;                       // 2 threads per candidate
    int idx = cand[b * NCAND + c];
    const float4* ev = (const float4*)(emb + (size_t)idx * EDIM + h * 64);
    double part = 0.0;
    #pragma unroll 4
    for (int j = 0; j < 16; j++) {
        float4 e = ev[j];
        int d = h * 64 + j * 4;
        part += qd[d] * (double)e.x + qd[d + 1] * (double)e.y
              + qd[d + 2] * (double)e.z + qd[d + 3] * (double)e.w;
    }
    part += __shfl_xor(part, 1);                     // combine halves
    if (h == 0) { sv[c] = part; si[c] = idx; }
    __syncthreads();

    if (t < NCAND) {                                 // rank among 128 (ties: low idx)
        double v = sv[t]; int id = si[t];
        int rank = 0;
        for (int j = 0; j < NCAND; j++) {
            double vj = sv[j]; int ij = si[j];
            rank += (vj > v || (vj == v && ij < id)) ? 1 : 0;
        }
        if (rank < TOPK) {
            out[(size_t)b * TOPK + rank] = (float)v;
            out[(size_t)BATCH * TOPK + (size_t)b * TOPK + rank] = (float)id;
        }
    }
}

extern "C" void kernel_launch(void* const* d_in, const int* in_sizes, int n_in,
                              void* d_out, int out_size, void* d_ws, size_t ws_size,
                              hipStream_t stream) {
    const int*   seq = (const int*)d_in[0];
    const int*   len = (const int*)d_in[1];
    const float* emb = (const float*)d_in[2];
    float* out = (float*)d_out;

    // ws: q_bf [4096*128 u16] | emb_bf [100000*128 u16] | cand [4096*128 i32]
    //     | q_f32 [4096*128 f32]   (~30.6 MB total)
    unsigned short* qbf  = (unsigned short*)d_ws;
    unsigned short* ebf  = qbf + (size_t)BATCH * EDIM;
    int*            cand = (int*)(ebf + (size_t)V_ITEMS * EDIM);
    float*          qf   = (float*)(cand + (size_t)BATCH * NCAND);

    conv_bf16 <<<(V_ITEMS * EDIM) / (256 * 8), 256, 0, stream>>>(emb, ebf);
    query_bf16<<<BATCH, EDIM, 0, stream>>>(seq, len, emb, qbf, qf);
    score_topk<<<(BATCH / MT) * VSPLIT, 768, 0, stream>>>(qbf, ebf, cand);
    rescore   <<<BATCH, 256, 0, stream>>>(qf, emb, cand, out);
}